// Round 3
// baseline (25.590 us; speedup 1.0000x reference)
//
#include <hip/hip_runtime.h>
#include <math.h>

// Problem constants (match reference)
constexpr int B_ = 8;
constexpr int N_ = 128;
constexpr int H_ = 256;
constexpr int W_ = 256;
constexpr int PIX = H_ * W_;                        // 65536 pixels per batch
constexpr int BLOCK = 256;
constexpr int PXT = 2;                              // pixels per thread
constexpr int PIX_PER_BLOCK = BLOCK * PXT;          // 512
constexpr int BPB = PIX / PIX_PER_BLOCK;            // 128 blocks per batch

// Pre-transform vortex params: (y, x, tau, sigma) -> (y, x, a, c)
// a = -log2(e)/sigma^2,  c = tau/(pi*sigma^2)
__global__ void prep_kernel(const float* __restrict__ vf, float4* __restrict__ sv) {
    const int i = blockIdx.x * blockDim.x + threadIdx.x;
    if (i < B_ * N_) {
        const float4 v = reinterpret_cast<const float4*>(vf)[i];
        const float inv_sig2 = 1.0f / (v.w * v.w);
        sv[i] = make_float4(v.x, v.y,
                            -1.4426950408889634f * inv_sig2,
                            v.z * 0.3183098861837907f * inv_sig2);
    }
}

__global__ __launch_bounds__(BLOCK) void gaussian_vorticity_kernel(
    const float4* __restrict__ sv,  // [B, N] transformed (y, x, a, c) in d_ws
    const float* __restrict__ pts,  // [B, H, W, 2]
    float* __restrict__ out)        // [B, H, W, 1]
{
    const int b = blockIdx.x / BPB;
    const int blkPix = (blockIdx.x % BPB) * PIX_PER_BLOCK;
    const int t = threadIdx.x;

    // 2 pixels per thread: float4 = (y0, x0, y1, x1)
    const float4 p01 = reinterpret_cast<const float4*>(
        pts + (size_t)b * PIX * 2)[(blkPix >> 1) + t];

    // Wave-uniform vortex pointer -> scalar (s_load) / broadcast loads, no LDS
    const float4* vb = sv + b * N_;

    float a0 = 0.0f, a1 = 0.0f, b0 = 0.0f, b1 = 0.0f;
#pragma unroll 8
    for (int n = 0; n < N_; ++n) {
        const float4 v = vb[n];
        const float dy0 = p01.x - v.x, dx0 = p01.y - v.y;
        const float dy1 = p01.z - v.x, dx1 = p01.w - v.y;
        const float e0 = __builtin_amdgcn_exp2f((dy0 * dy0 + dx0 * dx0) * v.z);
        const float e1 = __builtin_amdgcn_exp2f((dy1 * dy1 + dx1 * dx1) * v.z);
        if (n & 1) { b0 += e0 * v.w; b1 += e1 * v.w; }
        else       { a0 += e0 * v.w; a1 += e1 * v.w; }
    }

    float2* ob = reinterpret_cast<float2*>(out + (size_t)b * PIX + blkPix);
    ob[t] = make_float2(a0 + b0, a1 + b1);
}

extern "C" void kernel_launch(void* const* d_in, const int* in_sizes, int n_in,
                              void* d_out, int out_size, void* d_ws, size_t ws_size,
                              hipStream_t stream) {
    const float* vf  = (const float*)d_in[0];   // [B, N, 4]
    const float* pts = (const float*)d_in[1];   // [B, H, W, 2]
    float* out = (float*)d_out;                 // [B, H, W, 1]
    float4* sv = (float4*)d_ws;                 // [B, N] transformed params (16 KB)

    prep_kernel<<<(B_ * N_ + BLOCK - 1) / BLOCK, BLOCK, 0, stream>>>(vf, sv);

    const int grid = B_ * BPB;                  // 1024 blocks, 4 waves/SIMD
    gaussian_vorticity_kernel<<<grid, BLOCK, 0, stream>>>(sv, pts, out);
}

// Round 4
// 17.490 us; speedup vs baseline: 1.4631x; 1.4631x over previous
//
#include <hip/hip_runtime.h>
#include <math.h>

typedef float v2f __attribute__((ext_vector_type(2)));

// Problem constants (match reference)
constexpr int B_ = 8;
constexpr int N_ = 128;
constexpr int H_ = 256;
constexpr int W_ = 256;
constexpr int PIX = H_ * W_;                 // 65536 pixels per batch
constexpr int BLOCK = 512;                   // 8 waves: 4 do vortices 0-63, 4 do 64-127
constexpr int HALF = 256;
constexpr int PIX_PER_BLOCK = 1024;          // 4 px per thread (per half-block)
constexpr int BPB = PIX / PIX_PER_BLOCK;     // 64 blocks per batch

__global__ __launch_bounds__(BLOCK) void gaussian_vorticity_kernel(
    const float* __restrict__ vf,   // [B, N, 4] = (y, x, tau, sigma)
    const float* __restrict__ pts,  // [B, H, W, 2]
    float* __restrict__ out)        // [B, H, W, 1]
{
    __shared__ float4 sv[N_];        // (y, x, a=-log2e/sig2, c=tau/(pi*sig2))
    __shared__ float4 partials[HALF];

    const int b = blockIdx.x / BPB;
    const int blkPix = (blockIdx.x % BPB) * PIX_PER_BLOCK;
    const int t = threadIdx.x;
    const int half = t >> 8;         // 0: vortices [0,64), 1: [64,128)
    const int tl = t & (HALF - 1);

    // Stage transformed vortex params into LDS (first 128 threads)
    if (t < N_) {
        const float4 v = reinterpret_cast<const float4*>(vf)[b * N_ + t];
        const float inv_sig2 = 1.0f / (v.w * v.w);
        sv[t] = make_float4(v.x, v.y,
                            -1.4426950408889634f * inv_sig2,        // a
                            v.z * 0.3183098861837907f * inv_sig2);  // c
    }
    __syncthreads();

    // 4 pixels per thread (same pixels for both halves): float4 = 2 points each
    const float4* pbase = reinterpret_cast<const float4*>(
        pts + (size_t)b * PIX * 2) + (blkPix >> 1);
    const float4 p01 = pbase[tl];           // pixels 2tl, 2tl+1
    const float4 p23 = pbase[tl + HALF];    // pixels 512+2tl, 512+2tl+1

    // Repack for 2-wide packed fp32: (y0,y1), (x0,x1), ...
    const v2f py01 = {p01.x, p01.z}, px01 = {p01.y, p01.w};
    const v2f py23 = {p23.x, p23.z}, px23 = {p23.y, p23.w};

    const int nbase = half << 6;     // 0 or 64

    v2f acc01 = {0.0f, 0.0f}, acc23 = {0.0f, 0.0f};
#pragma unroll 8
    for (int n = 0; n < 64; ++n) {
        const float4 v = sv[nbase + n];   // broadcast ds_read_b128
        // pixels 0,1
        v2f dy = py01 - v.x;              // v_pk_add_f32 (scalar splat)
        v2f dx = px01 - v.y;
        v2f sq = dy * dy;
        sq += dx * dx;                    // v_pk_fma_f32 (fp-contract)
        v2f e;
        e.x = __builtin_amdgcn_exp2f(sq.x * v.z);
        e.y = __builtin_amdgcn_exp2f(sq.y * v.z);
        acc01 += e * v.w;
        // pixels 2,3
        dy = py23 - v.x;
        dx = px23 - v.y;
        sq = dy * dy;
        sq += dx * dx;
        e.x = __builtin_amdgcn_exp2f(sq.x * v.z);
        e.y = __builtin_amdgcn_exp2f(sq.y * v.z);
        acc23 += e * v.w;
    }

    // Combine the two vortex halves via LDS
    if (half == 1) {
        partials[tl] = make_float4(acc01.x, acc01.y, acc23.x, acc23.y);
    }
    __syncthreads();
    if (half == 0) {
        const float4 pr = partials[tl];
        float2* ob = reinterpret_cast<float2*>(out + (size_t)b * PIX + blkPix);
        ob[tl]        = make_float2(acc01.x + pr.x, acc01.y + pr.y);
        ob[tl + HALF] = make_float2(acc23.x + pr.z, acc23.y + pr.w);
    }
}

extern "C" void kernel_launch(void* const* d_in, const int* in_sizes, int n_in,
                              void* d_out, int out_size, void* d_ws, size_t ws_size,
                              hipStream_t stream) {
    const float* vf  = (const float*)d_in[0];   // [B, N, 4]
    const float* pts = (const float*)d_in[1];   // [B, H, W, 2]
    float* out = (float*)d_out;                 // [B, H, W, 1]

    const int grid = B_ * BPB;                  // 512 blocks x 512 thr = 4 waves/SIMD
    gaussian_vorticity_kernel<<<grid, BLOCK, 0, stream>>>(vf, pts, out);
}

// Round 5
// 16.976 us; speedup vs baseline: 1.5074x; 1.0302x over previous
//
#include <hip/hip_runtime.h>
#include <math.h>

typedef float v2f __attribute__((ext_vector_type(2)));

// Problem constants (match reference)
constexpr int B_ = 8;
constexpr int N_ = 128;
constexpr int H_ = 256;
constexpr int W_ = 256;
constexpr int PIX = H_ * W_;                 // 65536 pixels per batch
constexpr int BLOCK = 512;                   // 4 groups x 128 threads
constexpr int GROUPS = 4;                    // N-split: each group does 32 vortices
constexpr int GT = 128;                      // threads per group
constexpr int NPG = N_ / GROUPS;             // 32 vortices per group
constexpr int PPT = 4;                       // pixels per thread
constexpr int PIX_PER_BLOCK = GT * PPT;      // 512
constexpr int BPB = PIX / PIX_PER_BLOCK;     // 128 blocks per batch

__global__ __launch_bounds__(BLOCK, 8) void gaussian_vorticity_kernel(
    const float* __restrict__ vf,   // [B, N, 4] = (y, x, tau, sigma)
    const float* __restrict__ pts,  // [B, H, W, 2]
    float* __restrict__ out)        // [B, H, W, 1]
{
    __shared__ float4 sv[N_];              // (y, x, a=-log2e/sig2, c=tau/(pi*sig2))
    __shared__ float4 partials[GROUPS - 1][GT];

    const int b = blockIdx.x / BPB;
    const int blkPix = (blockIdx.x % BPB) * PIX_PER_BLOCK;
    const int t = threadIdx.x;
    const int g = t >> 7;                  // group 0..3 -> vortices [32g, 32g+32)
    const int tl = t & (GT - 1);

    // Stage transformed vortex params into LDS (first 128 threads)
    if (t < N_) {
        const float4 v = reinterpret_cast<const float4*>(vf)[b * N_ + t];
        const float inv_sig2 = 1.0f / (v.w * v.w);
        sv[t] = make_float4(v.x, v.y,
                            -1.4426950408889634f * inv_sig2,        // a
                            v.z * 0.3183098861837907f * inv_sig2);  // c
    }
    __syncthreads();

    // 4 pixels per thread (all groups cover the same 512 pixels; global loads
    // are L1 broadcast hits after the first group). float4 = 2 (y,x) points.
    const float4* pbase = reinterpret_cast<const float4*>(
        pts + (size_t)b * PIX * 2) + (blkPix >> 1);
    const float4 p01 = pbase[tl];          // pixels 2tl, 2tl+1
    const float4 p23 = pbase[tl + GT];     // pixels 256+2tl, 256+2tl+1

    // Repack for 2-wide packed fp32
    const v2f py01 = {p01.x, p01.z}, px01 = {p01.y, p01.w};
    const v2f py23 = {p23.x, p23.z}, px23 = {p23.y, p23.w};

    const float4* svg = sv + (g << 5);     // this group's 32 vortices

    v2f acc01 = {0.0f, 0.0f}, acc23 = {0.0f, 0.0f};
#pragma unroll 4
    for (int n = 0; n < NPG; ++n) {
        const float4 v = svg[n];           // broadcast ds_read_b128
        v2f dy = py01 - v.x;
        v2f dx = px01 - v.y;
        v2f sq = dy * dy;
        sq += dx * dx;
        v2f m = sq * v.z;
        v2f e;
        e.x = __builtin_amdgcn_exp2f(m.x);
        e.y = __builtin_amdgcn_exp2f(m.y);
        acc01 += e * v.w;

        dy = py23 - v.x;
        dx = px23 - v.y;
        sq = dy * dy;
        sq += dx * dx;
        m = sq * v.z;
        e.x = __builtin_amdgcn_exp2f(m.x);
        e.y = __builtin_amdgcn_exp2f(m.y);
        acc23 += e * v.w;
    }

    // Combine the 4 vortex-group partials via LDS
    if (g != 0) {
        partials[g - 1][tl] = make_float4(acc01.x, acc01.y, acc23.x, acc23.y);
    }
    __syncthreads();
    if (g == 0) {
#pragma unroll
        for (int k = 0; k < GROUPS - 1; ++k) {
            const float4 pr = partials[k][tl];
            acc01.x += pr.x; acc01.y += pr.y;
            acc23.x += pr.z; acc23.y += pr.w;
        }
        float2* ob = reinterpret_cast<float2*>(out + (size_t)b * PIX + blkPix);
        ob[tl]      = make_float2(acc01.x, acc01.y);
        ob[tl + GT] = make_float2(acc23.x, acc23.y);
    }
}

extern "C" void kernel_launch(void* const* d_in, const int* in_sizes, int n_in,
                              void* d_out, int out_size, void* d_ws, size_t ws_size,
                              hipStream_t stream) {
    const float* vf  = (const float*)d_in[0];   // [B, N, 4]
    const float* pts = (const float*)d_in[1];   // [B, H, W, 2]
    float* out = (float*)d_out;                 // [B, H, W, 1]

    const int grid = B_ * BPB;                  // 1024 blocks -> 8 waves/SIMD
    gaussian_vorticity_kernel<<<grid, BLOCK, 0, stream>>>(vf, pts, out);
}